// Round 3
// baseline (444.209 us; speedup 1.0000x reference)
//
#include <hip/hip_runtime.h>

constexpr int NN = 100000;   // nodes
constexpr int NE = 1600000;  // edges
constexpr int NG = 5000;     // graphs
constexpr int BKT = 64;      // dst-nodes per bucket
constexpr int NBKT = (NN + BKT - 1) / BKT;   // 1563
constexpr int NB = 128;      // hist/scatter blocks
constexpr int CHUNK = NE / NB;               // 12500 exact

typedef float v2f __attribute__((ext_vector_type(2)));

// ---- workspace layout (4B words), total ~7.4 MB ----
constexpr size_t OFF_G  = 0;                            // g      [NG*10]
constexpr size_t OFF_BH = 50048;                        // bh     [NB][NBKT]
constexpr size_t OFF_ST = OFF_BH + (size_t)NB * NBKT;   // starts [NBKT+1]
constexpr size_t OFF_PM = OFF_ST + NBKT + 1;            // perm   [NE]

// ---------------- pass A: per-block bucket histogram (+ zero g) ----------------
__global__ __launch_bounds__(256) void k_hist(const int* __restrict__ ei,
                                              int* __restrict__ bh,
                                              float* __restrict__ g) {
  __shared__ int lh[NBKT];
  for (int i = threadIdx.x; i < NBKT; i += 256) lh[i] = 0;
  __syncthreads();
  const int* dstp = ei + NE;
  int s = blockIdx.x * CHUNK;
  for (int i = s + threadIdx.x; i < s + CHUNK; i += 256)
    atomicAdd(&lh[dstp[i] >> 6], 1);                    // LDS int atomic
  int gid = blockIdx.x * 256 + threadIdx.x;             // zero g: 12,500 float4
  if (gid < 12500) ((float4*)g)[gid] = make_float4(0.f, 0.f, 0.f, 0.f);
  __syncthreads();
  int* out = bh + (size_t)blockIdx.x * NBKT;            // block-major: coalesced
  for (int k = threadIdx.x; k < NBKT; k += 256) out[k] = lh[k];
}

// ---------------- pass B1: per-bucket totals (grid-parallel) ----------------
__global__ __launch_bounds__(256) void k_btot(const int* __restrict__ bh,
                                              int* __restrict__ starts) {
  int k = blockIdx.x * 256 + threadIdx.x;
  if (k >= NBKT) return;
  int tot = 0;
  for (int b = 0; b < NB; b += 4) {                     // coalesced: k-consecutive
    int a0 = bh[(size_t)(b    ) * NBKT + k];
    int a1 = bh[(size_t)(b + 1) * NBKT + k];
    int a2 = bh[(size_t)(b + 2) * NBKT + k];
    int a3 = bh[(size_t)(b + 3) * NBKT + k];
    tot += a0 + a1 + a2 + a3;
  }
  starts[k] = tot;
}

// ---------------- pass B2: exclusive scan of 1563 totals ----------------
__global__ __launch_bounds__(1024) void k_sscan(int* __restrict__ starts) {
  __shared__ int s0[1024], s1[1024];
  int t = threadIdx.x;
  int k0 = 2 * t, k1 = 2 * t + 1;
  int tot0 = (k0 < NBKT) ? starts[k0] : 0;
  int tot1 = (k1 < NBKT) ? starts[k1] : 0;
  int ssum = tot0 + tot1;
  int* cur = s0; int* nxt = s1;
  cur[t] = ssum;
  __syncthreads();
  for (int off = 1; off < 1024; off <<= 1) {            // Hillis-Steele inclusive
    int v = cur[t];
    if (t >= off) v += cur[t - off];
    nxt[t] = v;
    __syncthreads();
    int* tmp = cur; cur = nxt; nxt = tmp;
  }
  int excl = cur[t] - ssum;
  if (k0 < NBKT) starts[k0] = excl;
  if (k1 <= NBKT) starts[k1] = excl + tot0;             // t=781 writes starts[NBKT]=NE
}

// ---------------- pass B3: per-(block,bucket) bases (grid-parallel) ----------------
__global__ __launch_bounds__(256) void k_bases(int* __restrict__ bh,
                                               const int* __restrict__ starts) {
  int k = blockIdx.x * 256 + threadIdx.x;
  if (k >= NBKT) return;
  int run = starts[k];
  for (int b = 0; b < NB; ++b) {
    size_t idx = (size_t)b * NBKT + k;
    int v = bh[idx];
    bh[idx] = run;
    run += v;
  }
}

// ---------------- pass C: scatter edge ids into bucket order ----------------
__global__ __launch_bounds__(256) void k_scatter(const int* __restrict__ ei,
                                                 const int* __restrict__ bh,
                                                 int* __restrict__ perm) {
  __shared__ int base[NBKT];
  __shared__ int cnt[NBKT];
  const int* row = bh + (size_t)blockIdx.x * NBKT;
  for (int k = threadIdx.x; k < NBKT; k += 256) { base[k] = row[k]; cnt[k] = 0; }
  __syncthreads();
  const int* dstp = ei + NE;
  int s = blockIdx.x * CHUNK;
  for (int i = s + threadIdx.x; i < s + CHUNK; i += 256) {
    int d = dstp[i];
    int k = d >> 6;
    int r = atomicAdd(&cnt[k], 1);                      // LDS atomic
    perm[base[k] + r] = i | ((d & 63) << 24);           // edge id (21b) | dst-low6 <<24
  }
}

// ---------------- pass D: edge MLP + fused node MLP + graph pooling ----------------
// Lane (ep,jp): ep = edge slot (6/wave), jp = output pair (10).
// Weights in LDS (4 KB); wrow asm-opaqued so LICM can't hoist them to regs
// (R0 lesson: pinned weight regs went to AGPRs, capped occupancy at 27%).
// Loop body = R1 structure: perm 2-deep, ei 1-deep, features IN-iteration
// (R2 lesson: 1-deep feature prefetch spilled to scratch, WRITE_SIZE 289KB->
// 3.4MB, regressed 190->216us. VGPR must stay ~44.)
// R2 post-mortem: occupancy was GRID-limited (1563 blocks x 4 waves = 6252
// waves < 8192 slots -> 76% at t=0, ~40% avg). Fix: 512-thread blocks ->
// 12504 waves, occupancy pinned ~100% for most of the kernel; co-resident
// waves hide the in-iteration gather latency (TLP, not ILP).
#define PK4(V, T) { \
  float4 wA = wt4[wrow + (T)];     \
  float4 wB = wt4[wrow + (T) + 1]; \
  a0 = __builtin_elementwise_fma(v2f{(V).x, (V).x}, v2f{wA.x, wA.y}, a0); \
  a1 = __builtin_elementwise_fma(v2f{(V).y, (V).y}, v2f{wA.z, wA.w}, a1); \
  a2 = __builtin_elementwise_fma(v2f{(V).z, (V).z}, v2f{wB.x, wB.y}, a2); \
  a3 = __builtin_elementwise_fma(v2f{(V).w, (V).w}, v2f{wB.z, wB.w}, a3); }

__global__ __launch_bounds__(512, 8) void k_edge(
    const int* __restrict__ ei,
    const float* __restrict__ nattr,
    const float* __restrict__ eattr,
    const float* __restrict__ Wm,
    const float* __restrict__ bm,
    const int* __restrict__ batch,
    const float* __restrict__ W1,
    const float* __restrict__ b1,
    const int* __restrict__ perm,
    const int* __restrict__ starts,
    float* __restrict__ g) {
  __shared__ float xt[20 * 65];    // padded rows
  __shared__ float gb[64 * 10];    // graph partials for this bucket's span
  __shared__ float4 wt4[250];      // weights: [jp][t] t=0..23 -> (W[2t],W[2t+1]) pair for cols 2jp,2jp+1
  __shared__ int s_se[2];
  __shared__ int s_bmin;
  for (int i = threadIdx.x; i < 20 * 65; i += 512) xt[i] = 0.f;
  for (int i = threadIdx.x; i < 640; i += 512) gb[i] = 0.f;
  if (threadIdx.x < 240) {
    int i = threadIdx.x;
    int j = i / 24, t = i - j * 24, k = 2 * t;
    wt4[j * 25 + t] = make_float4(Wm[k * 20 + 2 * j],       Wm[k * 20 + 2 * j + 1],
                                  Wm[(k + 1) * 20 + 2 * j], Wm[(k + 1) * 20 + 2 * j + 1]);
  }
  if (threadIdx.x < 2) s_se[threadIdx.x] = starts[blockIdx.x + threadIdx.x];
  int nbase = blockIdx.x * BKT;
  if (threadIdx.x == 0) s_bmin = batch[nbase];
  __syncthreads();
  int is = s_se[0], ie = s_se[1];

  int wave = threadIdx.x >> 6;     // 0..7
  int lane = threadIdx.x & 63;
  int ep = lane / 10;              // 0..6 (6 -> idle lane)
  int jp = lane - ep * 10;         // 0..9
  bool act = ep < 6;
  int epc = act ? ep : 0;

  v2f bj = {bm[2 * jp], bm[2 * jp + 1]};

  // perm 2-deep, ei 1-deep; 8 waves x 6 edges = stride 48.
  int base = is + wave * 6;
  int p0 = 0, p1 = 0, sv0 = 0;
  if (base < ie) {
    p0 = perm[min(base + epc, ie - 1)];
    sv0 = ei[p0 & 0xFFFFFF];
    p1 = (base + 48 < ie) ? perm[min(base + 48 + epc, ie - 1)] : p0;
  }
  while (base < ie) {
    int b2 = base + 96;
    int p2 = (b2 < ie) ? perm[min(b2 + epc, ie - 1)] : p1;   // perm 2 ahead
    int sN = (base + 48 < ie) ? ei[p1 & 0xFFFFFF] : sv0;     // src gather 1 ahead

    // this iteration's feature gathers (addresses arrived in previous iters)
    const float4* pe = (const float4*)(eattr + (size_t)(p0 & 0xFFFFFF) * 16);
    const float4* ps = (const float4*)(nattr + (size_t)sv0 * 16);
    float4 e0 = pe[0], e1 = pe[1], e2 = pe[2], e3 = pe[3];
    float4 n0 = ps[0], n1 = ps[1], n2 = ps[2], n3 = ps[3];
    int dl = (p0 >> 24) & 63;
    const float4* pd = (const float4*)(nattr + (size_t)(nbase + dl) * 16);
    float4 u0 = pd[0], u1 = pd[1], u2 = pd[2], u3 = pd[3];   // L1-hot

    int wrow = jp * 25;
    asm volatile("" : "+v"(wrow));   // defeat LICM of weight loads (keep them in LDS)

    v2f a0 = {0.f, 0.f}, a1 = {0.f, 0.f}, a2 = {0.f, 0.f}, a3 = {0.f, 0.f};
    PK4(n0, 0)  PK4(n1, 2)  PK4(n2, 4)  PK4(n3, 6)      // src feats  (k 0..15)
    PK4(u0, 8)  PK4(u1, 10) PK4(u2, 12) PK4(u3, 14)     // dst feats  (k 16..31)
    PK4(e0, 16) PK4(e1, 18) PK4(e2, 20) PK4(e3, 22)     // edge feats (k 32..47)
    v2f r = ((a0 + a1) + (a2 + a3)) + bj;

    bool valid = act && (base + epc < ie);
    float m0 = fmaxf(r.x, 0.f);
    float m1 = fmaxf(r.y, 0.f);
    if (valid && m0 > 0.f) atomicAdd(&xt[(2 * jp) * 65 + dl], m0);     // LDS
    if (valid && m1 > 0.f) atomicAdd(&xt[(2 * jp + 1) * 65 + dl], m1);

    base += 48; p0 = p1; p1 = p2; sv0 = sN;
  }
  __syncthreads();

  // ---- fused node MLP (20 -> 10, relu) + graph pre-aggregation ----
  int nn = min(BKT, NN - nbase);
  int bmin = s_bmin;
  if (threadIdx.x < 64 && (int)threadIdx.x < nn) {
    int node = threadIdx.x;
    float xi[20];
#pragma unroll
    for (int j = 0; j < 20; ++j) xi[j] = xt[j * 65 + node];
    float acc[10];
#pragma unroll
    for (int j = 0; j < 10; ++j) acc[j] = b1[j];
#pragma unroll
    for (int k = 0; k < 20; ++k) {
      float fk = xi[k];
#pragma unroll
      for (int j = 0; j < 10; ++j) acc[j] = fmaf(fk, W1[k * 10 + j], acc[j]);
    }
    int bn = batch[nbase + node];
    int d = bn - bmin;                                  // >= 0 (batch sorted)
    if (d < 64) {
#pragma unroll
      for (int j = 0; j < 10; ++j) {
        float m = fmaxf(acc[j], 0.f);
        if (m > 0.f) atomicAdd(&gb[d * 10 + j], m);     // LDS
      }
    } else {                                            // rare large jump
#pragma unroll
      for (int j = 0; j < 10; ++j) {
        float m = fmaxf(acc[j], 0.f);
        if (m > 0.f) unsafeAtomicAdd(&g[(size_t)bn * 10 + j], m);
      }
    }
  }
  __syncthreads();
  int glim = min(640, NG * 10 - bmin * 10);
  float* gp = g + (size_t)bmin * 10;
  for (int idx = threadIdx.x; idx < glim; idx += 512) {
    float v = gb[idx];
    if (v != 0.f) unsafeAtomicAdd(&gp[idx], v);         // ~40 sparse atomics/block
  }
}

// ---------------- graph MLP ----------------
__global__ __launch_bounds__(256) void k_graph(
    const float* __restrict__ g,
    const float* __restrict__ W2, const float* __restrict__ b2,
    const float* __restrict__ W3, const float* __restrict__ b3,
    float* __restrict__ out) {
  int i = blockIdx.x * 256 + threadIdx.x;
  if (i >= NG) return;
  float gi[10];
  const float2* pg = (const float2*)(g + (size_t)i * 10);
#pragma unroll
  for (int k = 0; k < 5; ++k) { float2 v = pg[k]; gi[2*k] = v.x; gi[2*k+1] = v.y; }
  float o = b3[0];
#pragma unroll
  for (int j = 0; j < 10; ++j) {
    float a = b2[j];
#pragma unroll
    for (int k = 0; k < 10; ++k) a = fmaf(gi[k], W2[k * 10 + j], a);
    o = fmaf(fmaxf(a, 0.f), W3[j], o);
  }
  out[i] = o;
}

extern "C" void kernel_launch(void* const* d_in, const int* in_sizes, int n_in,
                              void* d_out, int out_size, void* d_ws, size_t ws_size,
                              hipStream_t stream) {
  const int*   ei    = (const int*)  d_in[0];
  const float* nattr = (const float*)d_in[1];
  const float* eattr = (const float*)d_in[2];
  const int*   batch = (const int*)  d_in[3];
  const float* Wm    = (const float*)d_in[4];
  const float* bm    = (const float*)d_in[5];
  const float* W1    = (const float*)d_in[6];
  const float* b1    = (const float*)d_in[7];
  const float* W2    = (const float*)d_in[8];
  const float* b2    = (const float*)d_in[9];
  const float* W3    = (const float*)d_in[10];
  const float* b3    = (const float*)d_in[11];

  float* g      = (float*)d_ws + OFF_G;
  int*   bh     = (int*)d_ws + OFF_BH;
  int*   starts = (int*)d_ws + OFF_ST;
  int*   perm   = (int*)d_ws + OFF_PM;

  constexpr int SCAN_BLKS = (NBKT + 255) / 256;   // 7

  k_hist   <<<NB, 256, 0, stream>>>(ei, bh, g);
  k_btot   <<<SCAN_BLKS, 256, 0, stream>>>(bh, starts);
  k_sscan  <<<1, 1024, 0, stream>>>(starts);
  k_bases  <<<SCAN_BLKS, 256, 0, stream>>>(bh, starts);
  k_scatter<<<NB, 256, 0, stream>>>(ei, bh, perm);
  k_edge   <<<NBKT, 512, 0, stream>>>(ei, nattr, eattr, Wm, bm, batch, W1, b1,
                                      perm, starts, g);
  k_graph  <<<(NG + 255) / 256, 256, 0, stream>>>(g, W2, b2, W3, b3, (float*)d_out);
}

// Round 4
// 379.374 us; speedup vs baseline: 1.1709x; 1.1709x over previous
//
#include <hip/hip_runtime.h>

constexpr int NN = 100000;   // nodes
constexpr int NE = 1600000;  // edges
constexpr int NG = 5000;     // graphs
constexpr int BKT = 64;      // dst-nodes per bucket
constexpr int NBKT = (NN + BKT - 1) / BKT;   // 1563
constexpr int NB = 128;      // hist/scatter blocks
constexpr int CHUNK = NE / NB;               // 12500 exact

typedef float v2f __attribute__((ext_vector_type(2)));

// ---- workspace layout (4B words), total ~7.4 MB ----
constexpr size_t OFF_G  = 0;                            // g      [NG*10]
constexpr size_t OFF_BH = 50048;                        // bh     [NB][NBKT]
constexpr size_t OFF_ST = OFF_BH + (size_t)NB * NBKT;   // starts [NBKT+1]
constexpr size_t OFF_PM = OFF_ST + NBKT + 1;            // perm   [NE]

// ---------------- pass A: per-block bucket histogram (+ zero g) ----------------
__global__ __launch_bounds__(256) void k_hist(const int* __restrict__ ei,
                                              int* __restrict__ bh,
                                              float* __restrict__ g) {
  __shared__ int lh[NBKT];
  for (int i = threadIdx.x; i < NBKT; i += 256) lh[i] = 0;
  __syncthreads();
  const int* dstp = ei + NE;
  int s = blockIdx.x * CHUNK;
  for (int i = s + threadIdx.x; i < s + CHUNK; i += 256)
    atomicAdd(&lh[dstp[i] >> 6], 1);                    // LDS int atomic
  int gid = blockIdx.x * 256 + threadIdx.x;             // zero g: 12,500 float4
  if (gid < 12500) ((float4*)g)[gid] = make_float4(0.f, 0.f, 0.f, 0.f);
  __syncthreads();
  int* out = bh + (size_t)blockIdx.x * NBKT;            // block-major: coalesced
  for (int k = threadIdx.x; k < NBKT; k += 256) out[k] = lh[k];
}

// ---------------- pass B1: per-bucket totals (grid-parallel) ----------------
__global__ __launch_bounds__(256) void k_btot(const int* __restrict__ bh,
                                              int* __restrict__ starts) {
  int k = blockIdx.x * 256 + threadIdx.x;
  if (k >= NBKT) return;
  int tot = 0;
  for (int b = 0; b < NB; b += 4) {                     // coalesced: k-consecutive
    int a0 = bh[(size_t)(b    ) * NBKT + k];
    int a1 = bh[(size_t)(b + 1) * NBKT + k];
    int a2 = bh[(size_t)(b + 2) * NBKT + k];
    int a3 = bh[(size_t)(b + 3) * NBKT + k];
    tot += a0 + a1 + a2 + a3;
  }
  starts[k] = tot;
}

// ---------------- pass B2: exclusive scan of 1563 totals ----------------
__global__ __launch_bounds__(1024) void k_sscan(int* __restrict__ starts) {
  __shared__ int s0[1024], s1[1024];
  int t = threadIdx.x;
  int k0 = 2 * t, k1 = 2 * t + 1;
  int tot0 = (k0 < NBKT) ? starts[k0] : 0;
  int tot1 = (k1 < NBKT) ? starts[k1] : 0;
  int ssum = tot0 + tot1;
  int* cur = s0; int* nxt = s1;
  cur[t] = ssum;
  __syncthreads();
  for (int off = 1; off < 1024; off <<= 1) {            // Hillis-Steele inclusive
    int v = cur[t];
    if (t >= off) v += cur[t - off];
    nxt[t] = v;
    __syncthreads();
    int* tmp = cur; cur = nxt; nxt = tmp;
  }
  int excl = cur[t] - ssum;
  if (k0 < NBKT) starts[k0] = excl;
  if (k1 <= NBKT) starts[k1] = excl + tot0;             // t=781 writes starts[NBKT]=NE
}

// ---------------- pass B3: per-(block,bucket) bases (grid-parallel) ----------------
__global__ __launch_bounds__(256) void k_bases(int* __restrict__ bh,
                                               const int* __restrict__ starts) {
  int k = blockIdx.x * 256 + threadIdx.x;
  if (k >= NBKT) return;
  int run = starts[k];
  for (int b = 0; b < NB; ++b) {
    size_t idx = (size_t)b * NBKT + k;
    int v = bh[idx];
    bh[idx] = run;
    run += v;
  }
}

// ---------------- pass C: scatter edge ids into bucket order ----------------
__global__ __launch_bounds__(256) void k_scatter(const int* __restrict__ ei,
                                                 const int* __restrict__ bh,
                                                 int* __restrict__ perm) {
  __shared__ int base[NBKT];
  __shared__ int cnt[NBKT];
  const int* row = bh + (size_t)blockIdx.x * NBKT;
  for (int k = threadIdx.x; k < NBKT; k += 256) { base[k] = row[k]; cnt[k] = 0; }
  __syncthreads();
  const int* dstp = ei + NE;
  int s = blockIdx.x * CHUNK;
  for (int i = s + threadIdx.x; i < s + CHUNK; i += 256) {
    int d = dstp[i];
    int k = d >> 6;
    int r = atomicAdd(&cnt[k], 1);                      // LDS atomic
    perm[base[k] + r] = i | ((d & 63) << 24);           // edge id (21b) | dst-low6 <<24
  }
}

// ---------------- pass D: edge MLP + fused node MLP + graph pooling ----------------
// Lane (ep,jp): ep = edge slot (6/wave), jp = output pair (10).
// Weights in LDS (4 KB); wrow asm-opaqued so LICM can't hoist them to regs
// (R0 lesson: pinned weight regs went to AGPRs, capped occupancy at 27%).
// Body = R1 structure: perm 2-deep, ei 1-deep, features IN-iteration
// (R2 lesson: feature prefetch spilled; VGPR must stay ~44-64).
// 512-thread blocks: grid was occupancy-limiting at 256 (1563x4=6252 waves
// < 8192 slots); 1563x8=12504 waves pins occupancy (R3 confirmed 71%).
// R3 lesson: __launch_bounds__ arg2 is interpreted as min BLOCKS/CU (CUDA
// semantics) by hipcc — (512,8) demanded 64 waves/CU -> VGPR cap 32 ->
// 31.5 MB scratch spill. (512,4) = 32 waves/CU -> cap 64 >= the ~44 needed.
#define PK4(V, T) { \
  float4 wA = wt4[wrow + (T)];     \
  float4 wB = wt4[wrow + (T) + 1]; \
  a0 = __builtin_elementwise_fma(v2f{(V).x, (V).x}, v2f{wA.x, wA.y}, a0); \
  a1 = __builtin_elementwise_fma(v2f{(V).y, (V).y}, v2f{wA.z, wA.w}, a1); \
  a2 = __builtin_elementwise_fma(v2f{(V).z, (V).z}, v2f{wB.x, wB.y}, a2); \
  a3 = __builtin_elementwise_fma(v2f{(V).w, (V).w}, v2f{wB.z, wB.w}, a3); }

__global__ __launch_bounds__(512, 4) void k_edge(
    const int* __restrict__ ei,
    const float* __restrict__ nattr,
    const float* __restrict__ eattr,
    const float* __restrict__ Wm,
    const float* __restrict__ bm,
    const int* __restrict__ batch,
    const float* __restrict__ W1,
    const float* __restrict__ b1,
    const int* __restrict__ perm,
    const int* __restrict__ starts,
    float* __restrict__ g) {
  __shared__ float xt[20 * 65];    // padded rows
  __shared__ float gb[64 * 10];    // graph partials for this bucket's span
  __shared__ float4 wt4[250];      // weights: [jp][t] t=0..23 -> (W[2t],W[2t+1]) pair for cols 2jp,2jp+1
  __shared__ int s_se[2];
  __shared__ int s_bmin;
  for (int i = threadIdx.x; i < 20 * 65; i += 512) xt[i] = 0.f;
  for (int i = threadIdx.x; i < 640; i += 512) gb[i] = 0.f;
  if (threadIdx.x < 240) {
    int i = threadIdx.x;
    int j = i / 24, t = i - j * 24, k = 2 * t;
    wt4[j * 25 + t] = make_float4(Wm[k * 20 + 2 * j],       Wm[k * 20 + 2 * j + 1],
                                  Wm[(k + 1) * 20 + 2 * j], Wm[(k + 1) * 20 + 2 * j + 1]);
  }
  if (threadIdx.x < 2) s_se[threadIdx.x] = starts[blockIdx.x + threadIdx.x];
  int nbase = blockIdx.x * BKT;
  if (threadIdx.x == 0) s_bmin = batch[nbase];
  __syncthreads();
  int is = s_se[0], ie = s_se[1];

  int wave = threadIdx.x >> 6;     // 0..7
  int lane = threadIdx.x & 63;
  int ep = lane / 10;              // 0..6 (6 -> idle lane)
  int jp = lane - ep * 10;         // 0..9
  bool act = ep < 6;
  int epc = act ? ep : 0;

  v2f bj = {bm[2 * jp], bm[2 * jp + 1]};

  // perm 2-deep, ei 1-deep; 8 waves x 6 edges = stride 48.
  int base = is + wave * 6;
  int p0 = 0, p1 = 0, sv0 = 0;
  if (base < ie) {
    p0 = perm[min(base + epc, ie - 1)];
    sv0 = ei[p0 & 0xFFFFFF];
    p1 = (base + 48 < ie) ? perm[min(base + 48 + epc, ie - 1)] : p0;
  }
  while (base < ie) {
    int b2 = base + 96;
    int p2 = (b2 < ie) ? perm[min(b2 + epc, ie - 1)] : p1;   // perm 2 ahead
    int sN = (base + 48 < ie) ? ei[p1 & 0xFFFFFF] : sv0;     // src gather 1 ahead

    // this iteration's feature gathers (addresses arrived in previous iters)
    const float4* pe = (const float4*)(eattr + (size_t)(p0 & 0xFFFFFF) * 16);
    const float4* ps = (const float4*)(nattr + (size_t)sv0 * 16);
    float4 e0 = pe[0], e1 = pe[1], e2 = pe[2], e3 = pe[3];
    float4 n0 = ps[0], n1 = ps[1], n2 = ps[2], n3 = ps[3];
    int dl = (p0 >> 24) & 63;
    const float4* pd = (const float4*)(nattr + (size_t)(nbase + dl) * 16);
    float4 u0 = pd[0], u1 = pd[1], u2 = pd[2], u3 = pd[3];   // L1-hot

    int wrow = jp * 25;
    asm volatile("" : "+v"(wrow));   // defeat LICM of weight loads (keep them in LDS)

    v2f a0 = {0.f, 0.f}, a1 = {0.f, 0.f}, a2 = {0.f, 0.f}, a3 = {0.f, 0.f};
    PK4(n0, 0)  PK4(n1, 2)  PK4(n2, 4)  PK4(n3, 6)      // src feats  (k 0..15)
    PK4(u0, 8)  PK4(u1, 10) PK4(u2, 12) PK4(u3, 14)     // dst feats  (k 16..31)
    PK4(e0, 16) PK4(e1, 18) PK4(e2, 20) PK4(e3, 22)     // edge feats (k 32..47)
    v2f r = ((a0 + a1) + (a2 + a3)) + bj;

    bool valid = act && (base + epc < ie);
    float m0 = fmaxf(r.x, 0.f);
    float m1 = fmaxf(r.y, 0.f);
    if (valid && m0 > 0.f) atomicAdd(&xt[(2 * jp) * 65 + dl], m0);     // LDS
    if (valid && m1 > 0.f) atomicAdd(&xt[(2 * jp + 1) * 65 + dl], m1);

    base += 48; p0 = p1; p1 = p2; sv0 = sN;
  }
  __syncthreads();

  // ---- fused node MLP (20 -> 10, relu) + graph pre-aggregation ----
  int nn = min(BKT, NN - nbase);
  int bmin = s_bmin;
  if (threadIdx.x < 64 && (int)threadIdx.x < nn) {
    int node = threadIdx.x;
    float xi[20];
#pragma unroll
    for (int j = 0; j < 20; ++j) xi[j] = xt[j * 65 + node];
    float acc[10];
#pragma unroll
    for (int j = 0; j < 10; ++j) acc[j] = b1[j];
#pragma unroll
    for (int k = 0; k < 20; ++k) {
      float fk = xi[k];
#pragma unroll
      for (int j = 0; j < 10; ++j) acc[j] = fmaf(fk, W1[k * 10 + j], acc[j]);
    }
    int bn = batch[nbase + node];
    int d = bn - bmin;                                  // >= 0 (batch sorted)
    if (d < 64) {
#pragma unroll
      for (int j = 0; j < 10; ++j) {
        float m = fmaxf(acc[j], 0.f);
        if (m > 0.f) atomicAdd(&gb[d * 10 + j], m);     // LDS
      }
    } else {                                            // rare large jump
#pragma unroll
      for (int j = 0; j < 10; ++j) {
        float m = fmaxf(acc[j], 0.f);
        if (m > 0.f) unsafeAtomicAdd(&g[(size_t)bn * 10 + j], m);
      }
    }
  }
  __syncthreads();
  int glim = min(640, NG * 10 - bmin * 10);
  float* gp = g + (size_t)bmin * 10;
  for (int idx = threadIdx.x; idx < glim; idx += 512) {
    float v = gb[idx];
    if (v != 0.f) unsafeAtomicAdd(&gp[idx], v);         // ~40 sparse atomics/block
  }
}

// ---------------- graph MLP ----------------
__global__ __launch_bounds__(256) void k_graph(
    const float* __restrict__ g,
    const float* __restrict__ W2, const float* __restrict__ b2,
    const float* __restrict__ W3, const float* __restrict__ b3,
    float* __restrict__ out) {
  int i = blockIdx.x * 256 + threadIdx.x;
  if (i >= NG) return;
  float gi[10];
  const float2* pg = (const float2*)(g + (size_t)i * 10);
#pragma unroll
  for (int k = 0; k < 5; ++k) { float2 v = pg[k]; gi[2*k] = v.x; gi[2*k+1] = v.y; }
  float o = b3[0];
#pragma unroll
  for (int j = 0; j < 10; ++j) {
    float a = b2[j];
#pragma unroll
    for (int k = 0; k < 10; ++k) a = fmaf(gi[k], W2[k * 10 + j], a);
    o = fmaf(fmaxf(a, 0.f), W3[j], o);
  }
  out[i] = o;
}

extern "C" void kernel_launch(void* const* d_in, const int* in_sizes, int n_in,
                              void* d_out, int out_size, void* d_ws, size_t ws_size,
                              hipStream_t stream) {
  const int*   ei    = (const int*)  d_in[0];
  const float* nattr = (const float*)d_in[1];
  const float* eattr = (const float*)d_in[2];
  const int*   batch = (const int*)  d_in[3];
  const float* Wm    = (const float*)d_in[4];
  const float* bm    = (const float*)d_in[5];
  const float* W1    = (const float*)d_in[6];
  const float* b1    = (const float*)d_in[7];
  const float* W2    = (const float*)d_in[8];
  const float* b2    = (const float*)d_in[9];
  const float* W3    = (const float*)d_in[10];
  const float* b3    = (const float*)d_in[11];

  float* g      = (float*)d_ws + OFF_G;
  int*   bh     = (int*)d_ws + OFF_BH;
  int*   starts = (int*)d_ws + OFF_ST;
  int*   perm   = (int*)d_ws + OFF_PM;

  constexpr int SCAN_BLKS = (NBKT + 255) / 256;   // 7

  k_hist   <<<NB, 256, 0, stream>>>(ei, bh, g);
  k_btot   <<<SCAN_BLKS, 256, 0, stream>>>(bh, starts);
  k_sscan  <<<1, 1024, 0, stream>>>(starts);
  k_bases  <<<SCAN_BLKS, 256, 0, stream>>>(bh, starts);
  k_scatter<<<NB, 256, 0, stream>>>(ei, bh, perm);
  k_edge   <<<NBKT, 512, 0, stream>>>(ei, nattr, eattr, Wm, bm, batch, W1, b1,
                                      perm, starts, g);
  k_graph  <<<(NG + 255) / 256, 256, 0, stream>>>(g, W2, b2, W3, b3, (float*)d_out);
}